// Round 12
// baseline (2042.110 us; speedup 1.0000x reference)
//
#include <hip/hip_runtime.h>
#include <hip/hip_bf16.h>
#include <math.h>

#define L_  12
#define H_  12
#define D_  768
#define FF_ 3072
#define V_  32000
#define T_  1024
#define B_  2
#define BT_ (B_*T_)

typedef unsigned short ushort_t;
typedef unsigned int   uint_t;
typedef __bf16 bf16x8 __attribute__((ext_vector_type(8)));
typedef float  f32x4  __attribute__((ext_vector_type(4)));

__device__ __forceinline__ uint_t f2bf1(float f) {
    uint_t u = __builtin_bit_cast(uint_t, f);
    return (u + 0x7FFFu + ((u >> 16) & 1u)) >> 16;   // RNE truncate to bf16
}
__device__ __forceinline__ uint_t f2bf2(float lo, float hi) {
    return f2bf1(lo) | (f2bf1(hi) << 16);
}
__device__ __forceinline__ float bf2f(ushort_t u) {
    return __builtin_bit_cast(float, (uint_t)u << 16);
}

__device__ __forceinline__ void gl_lds16(const ushort_t* g, ushort_t* l) {
    __builtin_amdgcn_global_load_lds(
        (const __attribute__((address_space(1))) uint_t*)g,
        (__attribute__((address_space(3))) uint_t*)l, 16, 0, 0);
}

// ---------------- weight cast ----------------
__global__ __launch_bounds__(256) void cast_bf16(const float* __restrict__ in,
                                                 ushort_t* __restrict__ out, int n8)
{
    for (int i = blockIdx.x * 256 + threadIdx.x; i < n8; i += gridDim.x * 256) {
        const float4* p = (const float4*)(in + (size_t)i * 8);
        float4 a = p[0], b = p[1];
        *(uint4*)(out + (size_t)i * 8) =
            make_uint4(f2bf2(a.x,a.y), f2bf2(a.z,a.w), f2bf2(b.x,b.y), f2bf2(b.z,b.w));
    }
}

// ---------------- GEMM: C[M,N] = A[M,K] @ W[N,K]^T, bf16, BK=32, dbuf ----------------
#define EPI_F32   0
#define EPI_BF16  1
#define EPI_GELU  2
#define EPI_PART  3   // split-K bf16 partials: slice ks -> (ushort*)Cv + ks*BT_*D_
#define EPI_QKV   4   // Q,K -> Cv (bf16, stride 2304); V -> Vt transposed [bh][64][T]

template <int EPI, int BM, int KS>
__global__ __launch_bounds__(256) void gemm_bt(
    const ushort_t* __restrict__ A, const ushort_t* __restrict__ W,
    const float* R, void* Cv, ushort_t* __restrict__ Vt, int N, int K, int Kc)
{
    constexpr int MI = BM / 32;          // A-fragment tiles per wave
    constexpr int AH = BM * 32;          // ushorts per A buffer (BK=32)
    constexpr int BH = 128 * 32;
    __shared__ ushort_t As[2 * AH];      // linear dest (global_load_lds); content chunk-swizzled
    __shared__ ushort_t Bs[2 * BH];

    const int tid  = threadIdx.x;
    const int w    = tid >> 6;
    const int lane = tid & 63;

    // XCD-aware swizzle (nwg % 8 == 0 for all our shapes), M-fastest decode
    const int nwg = gridDim.x;
    int swz = (blockIdx.x & 7) * (nwg >> 3) + (blockIdx.x >> 3);
    constexpr int MT = 2048 / BM;
    const int mt = swz & (MT - 1);
    int rest     = swz / MT;
    const int ks = rest & (KS - 1);
    const int nt = rest / KS;
    const int m0 = mt * BM, n0 = nt * 128;
    const int kb = ks * Kc;

    // staging: 16-row issues; source col chunk XOR'd with ((row>>1)&3) so the
    // LINEAR lds write lands swizzled (2-way residual bank alias = free)
    const int srow = lane >> 2;                       // 0..15
    const int scol = ((lane & 3) ^ ((srow >> 1) & 3)) * 8;
    const ushort_t* gA = A + (size_t)(m0 + w * (BM / 4) + srow) * K + scol;
    const ushort_t* gW = W + (size_t)(n0 + w * 32 + srow) * K + scol;
    const size_t row16 = (size_t)16 * K;

    const int lr = lane & 15;
    const int lg = lane >> 4;
    const int wm = (w >> 1) * (BM / 2);
    const int wn = (w & 1) * 64;

    f32x4 acc[MI][4] = {};

    auto stage = [&](int buf, int k0) {
        ushort_t* lA = As + buf * AH + w * (BM / 4) * 32;
        ushort_t* lB = Bs + buf * BH + w * 1024;
        #pragma unroll
        for (int i = 0; i < BM / 64; ++i)
            gl_lds16(gA + k0 + i * row16, lA + i * 512);
        #pragma unroll
        for (int i = 0; i < 2; ++i)
            gl_lds16(gW + k0 + i * row16, lB + i * 512);
    };

    stage(0, kb);
    __syncthreads();
    int cur = 0;
    for (int k0 = kb; k0 < kb + Kc; k0 += 32) {
        if (k0 + 32 < kb + Kc) stage(cur ^ 1, k0 + 32);   // prefetch flies under MFMA below
        const ushort_t* Ab = As + cur * AH;
        const ushort_t* Bb = Bs + cur * BH;
        __builtin_amdgcn_s_setprio(1);
        {
            bf16x8 av[MI], bv[4];
            #pragma unroll
            for (int i = 0; i < MI; ++i) {
                int rr = wm + i * 16 + lr;
                int ch = lg ^ ((rr >> 1) & 3);
                av[i] = *(const bf16x8*)&Ab[rr * 32 + ch * 8];
            }
            #pragma unroll
            for (int j = 0; j < 4; ++j) {
                int rr = wn + j * 16 + lr;
                int ch = lg ^ ((rr >> 1) & 3);
                bv[j] = *(const bf16x8*)&Bb[rr * 32 + ch * 8];
            }
            #pragma unroll
            for (int i = 0; i < MI; ++i)
                #pragma unroll
                for (int j = 0; j < 4; ++j)
                    acc[i][j] = __builtin_amdgcn_mfma_f32_16x16x32_bf16(av[i], bv[j], acc[i][j], 0, 0, 0);
        }
        __builtin_amdgcn_s_setprio(0);
        __syncthreads();                               // drains prefetch + ends read phase
        cur ^= 1;
    }

    float*    Cf = (float*)Cv;
    ushort_t* Cb = (ushort_t*)Cv;
    ushort_t* Pp = (EPI == EPI_PART) ? ((ushort_t*)Cv + (size_t)ks * BT_ * D_) : nullptr;
    const int rbase = lg * 4;
    #pragma unroll
    for (int i = 0; i < MI; ++i) {
        #pragma unroll
        for (int j = 0; j < 4; ++j) {
            const int row0 = m0 + wm + i * 16 + rbase;
            const int col  = n0 + wn + j * 16 + lr;
            if (EPI == EPI_QKV) {
                if (col < 1536) {              // Q or K: bf16 into qkv (wave-uniform branch)
                    #pragma unroll
                    for (int r = 0; r < 4; ++r)
                        Cb[(size_t)(row0 + r) * 2304 + col] = (ushort_t)f2bf1(acc[i][j][r]);
                } else {                       // V: transposed into vt[bh][64][T], 4 t's per store
                    const int hh = (col - 1536) >> 6, dd = (col - 1536) & 63;
                    const int bb = row0 >> 10,        tt = row0 & 1023;
                    uint2 pk;
                    pk.x = f2bf2(acc[i][j][0], acc[i][j][1]);
                    pk.y = f2bf2(acc[i][j][2], acc[i][j][3]);
                    *(uint2*)&Vt[(((size_t)bb * H_ + hh) * 64 + dd) * T_ + tt] = pk;
                }
            } else {
                #pragma unroll
                for (int r = 0; r < 4; ++r) {
                    size_t idx = (size_t)(row0 + r) * N + col;
                    float v = acc[i][j][r];
                    if (EPI == EPI_F32)  Cf[idx] = v;
                    if (EPI == EPI_BF16) Cb[idx] = (ushort_t)f2bf1(v);
                    if (EPI == EPI_GELU) Cb[idx] = (ushort_t)f2bf1(0.5f * v * (1.0f + erff(v * 0.70710678118654752f)));
                    if (EPI == EPI_PART) Pp[idx] = (ushort_t)f2bf1(v);
                }
            }
        }
    }
}

// ---------------- lm_head GEMM: 256x256 tile, 8 waves, BK=64, dbuf, 64 MFMA/wave/barrier ----------------
__global__ __launch_bounds__(512, 2) void gemm256(
    const ushort_t* __restrict__ A, const ushort_t* __restrict__ W,
    float* __restrict__ C, int N, int K)
{
    __shared__ ushort_t Ls[2][2][256 * 64];   // [buf][A=0/B=1][256 rows x 64 k] = 128 KiB

    const int tid  = threadIdx.x;
    const int w    = tid >> 6;
    const int lane = tid & 63;

    // XCD swizzle (grid 1000 = 8 x 125), M-fastest decode (MT = 8)
    const int nwg = gridDim.x;
    int swz = (blockIdx.x & 7) * (nwg >> 3) + (blockIdx.x >> 3);
    const int mt = swz & 7;
    const int nt = swz >> 3;
    const int m0 = mt * 256, n0 = nt * 256;

    // staging: thread t covers row (t>>3) of a 64-row segment, source chunk XOR (row&7)
    const int trow = tid >> 3;                        // 0..63
    const int tchk = (tid & 7) ^ (trow & 7);
    const ushort_t* gA = A + (size_t)(m0 + trow) * K + tchk * 8;
    const ushort_t* gW = W + (size_t)(n0 + trow) * K + tchk * 8;

    const int lr = lane & 15;
    const int lg = lane >> 4;
    const int wm = (w >> 2) * 128;                    // 2 M-wave rows
    const int wn = (w & 3) * 64;                      // 4 N-wave cols

    f32x4 acc[8][4] = {};

    auto stage = [&](int buf, int k0) {
        #pragma unroll
        for (int seg = 0; seg < 4; ++seg) {           // rows seg*64 .. seg*64+63
            gl_lds16(gA + (size_t)(seg * 64) * K + k0, &Ls[buf][0][seg * 4096 + w * 512]);
            gl_lds16(gW + (size_t)(seg * 64) * K + k0, &Ls[buf][1][seg * 4096 + w * 512]);
        }
    };

    stage(0, 0);
    __syncthreads();
    int cur = 0;
    const int NT = K / 64;
    for (int t = 0; t < NT; ++t) {
        if (t + 1 < NT) stage(cur ^ 1, (t + 1) * 64);  // prefetch into other buffer
        const ushort_t* Ab = Ls[cur][0];
        const ushort_t* Bb = Ls[cur][1];
        bf16x8 bv[4][2];
        #pragma unroll
        for (int nf = 0; nf < 4; ++nf) {
            int rr = wn + nf * 16 + lr;
            #pragma unroll
            for (int kk = 0; kk < 2; ++kk) {
                int ch = (kk * 4 + lg) ^ (rr & 7);
                bv[nf][kk] = *(const bf16x8*)&Bb[rr * 64 + ch * 8];
            }
        }
        __builtin_amdgcn_s_setprio(1);
        #pragma unroll
        for (int mf = 0; mf < 8; ++mf) {
            int rr = wm + mf * 16 + lr;
            int ch0 = lg ^ (rr & 7);
            int ch1 = (4 + lg) ^ (rr & 7);
            bf16x8 a0 = *(const bf16x8*)&Ab[rr * 64 + ch0 * 8];
            bf16x8 a1 = *(const bf16x8*)&Ab[rr * 64 + ch1 * 8];
            #pragma unroll
            for (int nf = 0; nf < 4; ++nf) {
                acc[mf][nf] = __builtin_amdgcn_mfma_f32_16x16x32_bf16(a0, bv[nf][0], acc[mf][nf], 0, 0, 0);
                acc[mf][nf] = __builtin_amdgcn_mfma_f32_16x16x32_bf16(a1, bv[nf][1], acc[mf][nf], 0, 0, 0);
            }
        }
        __builtin_amdgcn_s_setprio(0);
        __syncthreads();                               // drains prefetch + ends read phase
        cur ^= 1;
    }

    const int rbase = lg * 4;
    #pragma unroll
    for (int mf = 0; mf < 8; ++mf) {
        #pragma unroll
        for (int nf = 0; nf < 4; ++nf) {
            #pragma unroll
            for (int r = 0; r < 4; ++r) {
                int row = m0 + wm + mf * 16 + rbase + r;
                int col = n0 + wn + nf * 16 + lr;
                C[(size_t)row * N + col] = acc[mf][nf][r];
            }
        }
    }
}

// ---------------- MFMA flash attention, no-LDS K/V (L2-resident), 1 wave / 16 q-rows ----------------
__global__ __launch_bounds__(64) void attn_mfma(const ushort_t* __restrict__ qkv,
    const ushort_t* __restrict__ vt, ushort_t* __restrict__ o)
{
    __shared__ ushort_t Ps[16 * 136];

    // bh-clustered XCD swizzle: 1536 blocks -> 8 chunks of 192 (3 bh each)
    int swz = (blockIdx.x & 7) * 192 + (blockIdx.x >> 3);
    const int bh  = swz >> 6;
    const int qtl = 63 - (swz & 63);     // heavy q-tiles first within chunk
    const int b   = bh / H_;
    const int h   = bh % H_;
    const int lane = threadIdx.x;
    const int l15  = lane & 15;
    const int lg   = lane >> 4;
    const int qbase = qtl * 16;
    const int qlast = qbase + 15;

    const ushort_t* qp = qkv + ((size_t)(b * T_) + qbase + l15) * 2304 + h * 64 + lg * 8;
    bf16x8 qf0 = *(const bf16x8*)qp;
    bf16x8 qf1 = *(const bf16x8*)(qp + 32);

    f32x4 od[4] = {};
    float mr[4] = {-INFINITY, -INFINITY, -INFINITY, -INFINITY};
    float lr[4] = {0.f, 0.f, 0.f, 0.f};

    const ushort_t* kbase = qkv + (size_t)(b * T_) * 2304 + 768 + h * 64;
    const ushort_t* vbase = vt + (size_t)bh * 64 * T_;
    const float SC = 0.18033688011112042f;   // 0.125 * log2(e): softmax in exp2 domain

    for (int j0 = 0; j0 <= qlast; j0 += 128) {
        f32x4 s[8];
        __builtin_amdgcn_s_setprio(1);
        #pragma unroll
        for (int n = 0; n < 8; ++n) {
            if (j0 + 16 * n <= qlast) {
                const ushort_t* kr = kbase + (size_t)(j0 + 16 * n + l15) * 2304 + lg * 8;
                bf16x8 kf0 = *(const bf16x8*)kr;
                bf16x8 kf1 = *(const bf16x8*)(kr + 32);
                f32x4 a = {};
                a = __builtin_amdgcn_mfma_f32_16x16x32_bf16(qf0, kf0, a, 0, 0, 0);
                a = __builtin_amdgcn_mfma_f32_16x16x32_bf16(qf1, kf1, a, 0, 0, 0);
                s[n] = a;
            } else {
                s[n] = f32x4{-INFINITY, -INFINITY, -INFINITY, -INFINITY};
            }
        }
        __builtin_amdgcn_s_setprio(0);

        #pragma unroll
        for (int n = 0; n < 8; ++n) {
            #pragma unroll
            for (int r = 0; r < 4; ++r) {
                float v = s[n][r] * SC;
                int jg = j0 + 16 * n + l15;
                int qg = qbase + lg * 4 + r;
                if (jg > qg) v = -INFINITY;
                s[n][r] = v;
            }
        }

        float al[4];
        #pragma unroll
        for (int r = 0; r < 4; ++r) {
            float tm = fmaxf(fmaxf(fmaxf(s[0][r], s[1][r]), fmaxf(s[2][r], s[3][r])),
                             fmaxf(fmaxf(s[4][r], s[5][r]), fmaxf(s[6][r], s[7][r])));
            tm = fmaxf(tm, __shfl_xor(tm, 1, 64));
            tm = fmaxf(tm, __shfl_xor(tm, 2, 64));
            tm = fmaxf(tm, __shfl_xor(tm, 4, 64));
            tm = fmaxf(tm, __shfl_xor(tm, 8, 64));
            float mn = fmaxf(mr[r], tm);
            al[r] = exp2f(mr[r] - mn);
            mr[r] = mn;
        }
        #pragma unroll
        for (int n = 0; n < 8; ++n)
            #pragma unroll
            for (int r = 0; r < 4; ++r)
                s[n][r] = exp2f(s[n][r] - mr[r]);
        #pragma unroll
        for (int r = 0; r < 4; ++r) {
            float ps = (s[0][r] + s[1][r]) + (s[2][r] + s[3][r]);
            ps += (s[4][r] + s[5][r]) + (s[6][r] + s[7][r]);
            ps += __shfl_xor(ps, 1, 64);
            ps += __shfl_xor(ps, 2, 64);
            ps += __shfl_xor(ps, 4, 64);
            ps += __shfl_xor(ps, 8, 64);
            lr[r] = lr[r] * al[r] + ps;
        }
        #pragma unroll
        for (int n = 0; n < 4; ++n)
            #pragma unroll
            for (int r = 0; r < 4; ++r)
                od[n][r] *= al[r];

        // P -> LDS rows (q = lg*4+r, j fast) for the PV A-fragment
        #pragma unroll
        for (int n = 0; n < 8; ++n)
            #pragma unroll
            for (int r = 0; r < 4; ++r)
                Ps[(lg * 4 + r) * 136 + 16 * n + l15] = (ushort_t)f2bf1(s[n][r]);

        __builtin_amdgcn_s_setprio(1);
        #pragma unroll
        for (int kc = 0; kc < 4; ++kc) {
            if (j0 + kc * 32 <= qlast) {
                bf16x8 pa = *(const bf16x8*)&Ps[l15 * 136 + kc * 32 + lg * 8];
                #pragma unroll
                for (int nn = 0; nn < 4; ++nn) {
                    bf16x8 vf = *(const bf16x8*)&vbase[(size_t)(16 * nn + l15) * T_ + j0 + kc * 32 + lg * 8];
                    od[nn] = __builtin_amdgcn_mfma_f32_16x16x32_bf16(pa, vf, od[nn], 0, 0, 0);
                }
            }
        }
        __builtin_amdgcn_s_setprio(0);
    }

    #pragma unroll
    for (int r = 0; r < 4; ++r) {
        float inv = 1.0f / lr[r];
        int row = qbase + lg * 4 + r;
        ushort_t* op = o + ((size_t)(b * T_ + row)) * 768 + h * 64 + l15;
        #pragma unroll
        for (int nn = 0; nn < 4; ++nn)
            op[16 * nn] = (ushort_t)f2bf1(od[nn][r] * inv);
    }
}

// ---------------- LN core (shared) ----------------
__device__ __forceinline__ void ln_body(float v0, float v1, float v2,
    const float* __restrict__ w, const float* __restrict__ bia,
    ushort_t* __restrict__ orow, int tid)
{
    float s  = v0 + v1 + v2;
    float s2 = v0 * v0 + v1 * v1 + v2 * v2;
    #pragma unroll
    for (int off = 32; off > 0; off >>= 1) {
        s  += __shfl_down(s,  off, 64);
        s2 += __shfl_down(s2, off, 64);
    }
    __shared__ float sh[8];
    const int wave = tid >> 6;
    if ((tid & 63) == 0) { sh[wave] = s; sh[4 + wave] = s2; }
    __syncthreads();
    float S  = sh[0] + sh[1] + sh[2] + sh[3];
    float S2 = sh[4] + sh[5] + sh[6] + sh[7];
    float mean = S * (1.f / 768.f);
    float var  = S2 * (1.f / 768.f) - mean * mean;
    float inv  = rsqrtf(var + 1e-5f);
    orow[tid]       = (ushort_t)f2bf1((v0 - mean) * inv * w[tid]       + bia[tid]);
    orow[tid + 256] = (ushort_t)f2bf1((v1 - mean) * inv * w[tid + 256] + bia[tid + 256]);
    orow[tid + 512] = (ushort_t)f2bf1((v2 - mean) * inv * w[tid + 512] + bia[tid + 512]);
}

// ---------------- fused: x += P0+P1+P2+P3 (bf16 partials) ; h = LN(x) ----------------
__global__ __launch_bounds__(256) void ln_red4(float* __restrict__ x,
    const ushort_t* __restrict__ P, const float* __restrict__ w,
    const float* __restrict__ bia, ushort_t* __restrict__ out)
{
    const int row = blockIdx.x;
    const int tid = threadIdx.x;
    const size_t base = (size_t)row * 768;
    const size_t st = (size_t)BT_ * D_;
    float v0 = x[base + tid];
    float v1 = x[base + tid + 256];
    float v2 = x[base + tid + 512];
    #pragma unroll
    for (int p = 0; p < 4; ++p) {
        v0 += bf2f(P[p * st + base + tid]);
        v1 += bf2f(P[p * st + base + tid + 256]);
        v2 += bf2f(P[p * st + base + tid + 512]);
    }
    x[base + tid]       = v0;
    x[base + tid + 256] = v1;
    x[base + tid + 512] = v2;
    ln_body(v0, v1, v2, w, bia, out + base, tid);
}

// ---------------- fused embedding + first LN ----------------
__global__ __launch_bounds__(256) void embed_ln(const int* __restrict__ ids,
    const float* __restrict__ tok, const float* __restrict__ pos,
    const float* __restrict__ w, const float* __restrict__ bia,
    float* __restrict__ x, ushort_t* __restrict__ out)
{
    const int bt = blockIdx.x;
    const int t  = bt % T_;
    const int id = ids[bt];
    const int tid = threadIdx.x;
    const float* tr = tok + (size_t)id * 768;
    const float* pr = pos + (size_t)t * 768;
    const size_t base = (size_t)bt * 768;
    float v0 = tr[tid]       + pr[tid];
    float v1 = tr[tid + 256] + pr[tid + 256];
    float v2 = tr[tid + 512] + pr[tid + 512];
    x[base + tid]       = v0;
    x[base + tid + 256] = v1;
    x[base + tid + 512] = v2;
    ln_body(v0, v1, v2, w, bia, out + base, tid);
}

// ---------------- launcher ----------------
extern "C" void kernel_launch(void* const* d_in, const int* in_sizes, int n_in,
                              void* d_out, int out_size, void* d_ws, size_t ws_size,
                              hipStream_t stream)
{
    const int*   ids   = (const int*)  d_in[0];
    const float* tok   = (const float*)d_in[1];
    const float* pos   = (const float*)d_in[2];
    const float* ln1w  = (const float*)d_in[3];
    const float* ln1b  = (const float*)d_in[4];
    const float* qkvw  = (const float*)d_in[5];
    const float* outw  = (const float*)d_in[6];
    const float* ln2w  = (const float*)d_in[7];
    const float* ln2b  = (const float*)d_in[8];
    const float* upw   = (const float*)d_in[9];
    const float* downw = (const float*)d_in[10];
    const float* lnfw  = (const float*)d_in[11];
    const float* lnfb  = (const float*)d_in[12];
    float* out = (float*)d_out;

    // workspace layout (~290 MB of ~1 GiB d_ws)
    char* ws = (char*)d_ws;
    ushort_t* h    = (ushort_t*)ws;                               //  3,145,728 B
    float*    x    = (float*)   (ws + 3145728);                   //  6,291,456 B
    ushort_t* qkv  = (ushort_t*)(ws + 9437184);                   //  9,437,184 B
    ushort_t* o    = qkv  + (size_t)BT_ * 3 * D_;                 //  3,145,728 B
    ushort_t* vt   = o    + (size_t)BT_ * D_;                     //  3,145,728 B
    ushort_t* ffh  = vt   + (size_t)B_ * H_ * 64 * T_;            // 12,582,912 B
    ushort_t* P4   = (ushort_t*)(ws + 37748736);                  // 12,582,912 B (4 bf16 partials)
    ushort_t* tokW = (ushort_t*)(ws + 67108864);                  // 49,152,000 B
    ushort_t* qkvwB  = (ushort_t*)(ws + 117440512);               // 42,467,328 B
    ushort_t* outwB  = qkvwB  + (size_t)L_ * 3 * D_ * D_;         // 14,155,776 B
    ushort_t* upwB   = outwB  + (size_t)L_ * D_ * D_;             // 56,623,104 B
    ushort_t* downwB = upwB   + (size_t)L_ * FF_ * D_;            // 56,623,104 B

    // bulk pre-cast of all layer weights (bf16 total 170 MB -> L3-resident)
    cast_bf16<<<2048, 256, 0, stream>>>(qkvw,  qkvwB,  L_ * 3 * D_ * D_ / 8);
    cast_bf16<<<2048, 256, 0, stream>>>(outw,  outwB,  L_ * D_ * D_ / 8);
    cast_bf16<<<2048, 256, 0, stream>>>(upw,   upwB,   L_ * FF_ * D_ / 8);
    cast_bf16<<<2048, 256, 0, stream>>>(downw, downwB, L_ * D_ * FF_ / 8);

    for (int l = 0; l < L_; ++l) {
        if (l == 0)
            embed_ln<<<BT_, 256, 0, stream>>>(ids, tok, pos, ln1w, ln1b, x, h);
        else
            ln_red4<<<BT_, 256, 0, stream>>>(x, P4, ln1w + l * D_, ln1b + l * D_, h);

        // QKV GEMM with fused V-transpose epilogue (BM=64: grid 576)
        gemm_bt<EPI_QKV, 64, 1><<<32 * (3 * D_ / 128), 256, 0, stream>>>(
            h, qkvwB + (size_t)l * 3 * D_ * D_, nullptr, qkv, vt, 3 * D_, D_, D_);

        attn_mfma<<<B_ * H_ * (T_ / 16), 64, 0, stream>>>(qkv, vt, o);

        // out-proj: split-K KS=4 (grid 768), bf16 partials -> P4
        gemm_bt<EPI_PART, 64, 4><<<32 * (D_ / 128) * 4, 256, 0, stream>>>(
            o, outwB + (size_t)l * D_ * D_, nullptr, P4, nullptr, D_, D_, D_ / 4);

        ln_red4<<<BT_, 256, 0, stream>>>(x, P4, ln2w + l * D_, ln2b + l * D_, h);

        gemm_bt<EPI_GELU, 64, 1><<<32 * (FF_ / 128), 256, 0, stream>>>(
            h, upwB + (size_t)l * FF_ * D_, nullptr, ffh, nullptr, FF_, D_, D_);

        // down-proj: split-K KS=4 (grid 768), bf16 partials -> P4
        gemm_bt<EPI_PART, 64, 4><<<32 * (D_ / 128) * 4, 256, 0, stream>>>(
            ffh, downwB + (size_t)l * D_ * FF_, nullptr, P4, nullptr, D_, FF_, FF_ / 4);
    }

    ln_red4<<<BT_, 256, 0, stream>>>(x, P4, lnfw, lnfb, h);

    cast_bf16<<<2048, 256, 0, stream>>>(tok, tokW, V_ * D_ / 8);
    gemm256<<<(2048 / 256) * (V_ / 256), 512, 0, stream>>>(h, tokW, out, V_, D_);
}

// Round 13
// 1929.108 us; speedup vs baseline: 1.0586x; 1.0586x over previous
//
#include <hip/hip_runtime.h>
#include <hip/hip_bf16.h>
#include <math.h>

#define L_  12
#define H_  12
#define D_  768
#define FF_ 3072
#define V_  32000
#define T_  1024
#define B_  2
#define BT_ (B_*T_)

typedef unsigned short ushort_t;
typedef unsigned int   uint_t;
typedef __bf16 bf16x8 __attribute__((ext_vector_type(8)));
typedef float  f32x4  __attribute__((ext_vector_type(4)));

__device__ __forceinline__ uint_t f2bf1(float f) {
    uint_t u = __builtin_bit_cast(uint_t, f);
    return (u + 0x7FFFu + ((u >> 16) & 1u)) >> 16;   // RNE truncate to bf16
}
__device__ __forceinline__ uint_t f2bf2(float lo, float hi) {
    return f2bf1(lo) | (f2bf1(hi) << 16);
}
__device__ __forceinline__ float bf2f(ushort_t u) {
    return __builtin_bit_cast(float, (uint_t)u << 16);
}

__device__ __forceinline__ void gl_lds16(const ushort_t* g, ushort_t* l) {
    __builtin_amdgcn_global_load_lds(
        (const __attribute__((address_space(1))) uint_t*)g,
        (__attribute__((address_space(3))) uint_t*)l, 16, 0, 0);
}

// ---------------- weight cast ----------------
__global__ __launch_bounds__(256) void cast_bf16(const float* __restrict__ in,
                                                 ushort_t* __restrict__ out, int n8)
{
    for (int i = blockIdx.x * 256 + threadIdx.x; i < n8; i += gridDim.x * 256) {
        const float4* p = (const float4*)(in + (size_t)i * 8);
        float4 a = p[0], b = p[1];
        *(uint4*)(out + (size_t)i * 8) =
            make_uint4(f2bf2(a.x,a.y), f2bf2(a.z,a.w), f2bf2(b.x,b.y), f2bf2(b.z,b.w));
    }
}

// one layer's {qkv_w, out_w, up_w, down_w} -> contiguous bf16 buffer (L2-warm for this layer)
__global__ __launch_bounds__(256) void cast_layer(const float* __restrict__ q,
    const float* __restrict__ o, const float* __restrict__ u, const float* __restrict__ d,
    ushort_t* __restrict__ out)
{
    const int N0 = 3*D_*D_/8, N1 = N0 + D_*D_/8, N2 = N1 + FF_*D_/8, N3 = N2 + D_*FF_/8;
    for (int i = blockIdx.x * 256 + threadIdx.x; i < N3; i += gridDim.x * 256) {
        const float* src;
        if      (i < N0) src = q + (size_t)i * 8;
        else if (i < N1) src = o + (size_t)(i - N0) * 8;
        else if (i < N2) src = u + (size_t)(i - N1) * 8;
        else             src = d + (size_t)(i - N2) * 8;
        const float4* p = (const float4*)src;
        float4 a = p[0], b = p[1];
        *(uint4*)(out + (size_t)i * 8) =
            make_uint4(f2bf2(a.x,a.y), f2bf2(a.z,a.w), f2bf2(b.x,b.y), f2bf2(b.z,b.w));
    }
}

// ---------------- GEMM: C[M,N] = A[M,K] @ W[N,K]^T, bf16, BK=32, dbuf ----------------
#define EPI_F32   0
#define EPI_BF16  1
#define EPI_GELU  2
#define EPI_PART  3   // split-K bf16 partials: slice ks -> (ushort*)Cv + ks*BT_*D_
#define EPI_QKV   4   // Q,K -> Cv (bf16, stride 2304); V -> Vt transposed [bh][64][T]

template <int EPI, int BM, int KS>
__global__ __launch_bounds__(256) void gemm_bt(
    const ushort_t* __restrict__ A, const ushort_t* __restrict__ W,
    const float* R, void* Cv, ushort_t* __restrict__ Vt, int N, int K, int Kc)
{
    constexpr int MI = BM / 32;          // A-fragment tiles per wave
    constexpr int AH = BM * 32;          // ushorts per A buffer (BK=32)
    constexpr int BH = 128 * 32;
    __shared__ ushort_t As[2 * AH];      // linear dest (global_load_lds); content chunk-swizzled
    __shared__ ushort_t Bs[2 * BH];

    const int tid  = threadIdx.x;
    const int w    = tid >> 6;
    const int lane = tid & 63;

    // XCD-aware swizzle (nwg % 8 == 0 for all our shapes), M-fastest decode
    const int nwg = gridDim.x;
    int swz = (blockIdx.x & 7) * (nwg >> 3) + (blockIdx.x >> 3);
    constexpr int MT = 2048 / BM;
    const int mt = swz & (MT - 1);
    int rest     = swz / MT;
    const int ks = rest & (KS - 1);
    const int nt = rest / KS;
    const int m0 = mt * BM, n0 = nt * 128;
    const int kb = ks * Kc;

    // staging: 16-row issues; source col chunk XOR'd with ((row>>1)&3) so the
    // LINEAR lds write lands swizzled (2-way residual bank alias = free)
    const int srow = lane >> 2;                       // 0..15
    const int scol = ((lane & 3) ^ ((srow >> 1) & 3)) * 8;
    const ushort_t* gA = A + (size_t)(m0 + w * (BM / 4) + srow) * K + scol;
    const ushort_t* gW = W + (size_t)(n0 + w * 32 + srow) * K + scol;
    const size_t row16 = (size_t)16 * K;

    const int lr = lane & 15;
    const int lg = lane >> 4;
    const int wm = (w >> 1) * (BM / 2);
    const int wn = (w & 1) * 64;

    f32x4 acc[MI][4] = {};

    auto stage = [&](int buf, int k0) {
        ushort_t* lA = As + buf * AH + w * (BM / 4) * 32;
        ushort_t* lB = Bs + buf * BH + w * 1024;
        #pragma unroll
        for (int i = 0; i < BM / 64; ++i)
            gl_lds16(gA + k0 + i * row16, lA + i * 512);
        #pragma unroll
        for (int i = 0; i < 2; ++i)
            gl_lds16(gW + k0 + i * row16, lB + i * 512);
    };

    stage(0, kb);
    __syncthreads();
    int cur = 0;
    for (int k0 = kb; k0 < kb + Kc; k0 += 32) {
        if (k0 + 32 < kb + Kc) stage(cur ^ 1, k0 + 32);   // prefetch flies under MFMA below
        const ushort_t* Ab = As + cur * AH;
        const ushort_t* Bb = Bs + cur * BH;
        __builtin_amdgcn_s_setprio(1);
        {
            bf16x8 av[MI], bv[4];
            #pragma unroll
            for (int i = 0; i < MI; ++i) {
                int rr = wm + i * 16 + lr;
                int ch = lg ^ ((rr >> 1) & 3);
                av[i] = *(const bf16x8*)&Ab[rr * 32 + ch * 8];
            }
            #pragma unroll
            for (int j = 0; j < 4; ++j) {
                int rr = wn + j * 16 + lr;
                int ch = lg ^ ((rr >> 1) & 3);
                bv[j] = *(const bf16x8*)&Bb[rr * 32 + ch * 8];
            }
            #pragma unroll
            for (int i = 0; i < MI; ++i)
                #pragma unroll
                for (int j = 0; j < 4; ++j)
                    acc[i][j] = __builtin_amdgcn_mfma_f32_16x16x32_bf16(av[i], bv[j], acc[i][j], 0, 0, 0);
        }
        __builtin_amdgcn_s_setprio(0);
        __syncthreads();                               // drains prefetch + ends read phase
        cur ^= 1;
    }

    float*    Cf = (float*)Cv;
    ushort_t* Cb = (ushort_t*)Cv;
    ushort_t* Pp = (EPI == EPI_PART) ? ((ushort_t*)Cv + (size_t)ks * BT_ * D_) : nullptr;
    const int rbase = lg * 4;
    #pragma unroll
    for (int i = 0; i < MI; ++i) {
        #pragma unroll
        for (int j = 0; j < 4; ++j) {
            const int row0 = m0 + wm + i * 16 + rbase;
            const int col  = n0 + wn + j * 16 + lr;
            if (EPI == EPI_QKV) {
                if (col < 1536) {              // Q or K: bf16 into qkv (wave-uniform branch)
                    #pragma unroll
                    for (int r = 0; r < 4; ++r)
                        Cb[(size_t)(row0 + r) * 2304 + col] = (ushort_t)f2bf1(acc[i][j][r]);
                } else {                       // V: transposed into vt[bh][64][T], 4 t's per store
                    const int hh = (col - 1536) >> 6, dd = (col - 1536) & 63;
                    const int bb = row0 >> 10,        tt = row0 & 1023;
                    uint2 pk;
                    pk.x = f2bf2(acc[i][j][0], acc[i][j][1]);
                    pk.y = f2bf2(acc[i][j][2], acc[i][j][3]);
                    *(uint2*)&Vt[(((size_t)bb * H_ + hh) * 64 + dd) * T_ + tt] = pk;
                }
            } else {
                #pragma unroll
                for (int r = 0; r < 4; ++r) {
                    size_t idx = (size_t)(row0 + r) * N + col;
                    float v = acc[i][j][r];
                    if (EPI == EPI_F32)  Cf[idx] = v;
                    if (EPI == EPI_BF16) Cb[idx] = (ushort_t)f2bf1(v);
                    if (EPI == EPI_GELU) Cb[idx] = (ushort_t)f2bf1(0.5f * v * (1.0f + erff(v * 0.70710678118654752f)));
                    if (EPI == EPI_PART) Pp[idx] = (ushort_t)f2bf1(v);
                }
            }
        }
    }
}

// ---------------- lm_head GEMM: 256x256 tile, 8 waves, BK=64, dbuf, 64 MFMA/wave/barrier ----------------
__global__ __launch_bounds__(512, 2) void gemm256(
    const ushort_t* __restrict__ A, const ushort_t* __restrict__ W,
    float* __restrict__ C, int N, int K)
{
    __shared__ ushort_t Ls[2][2][256 * 64];   // [buf][A=0/B=1][256 rows x 64 k] = 128 KiB

    const int tid  = threadIdx.x;
    const int w    = tid >> 6;
    const int lane = tid & 63;

    // XCD swizzle (grid 1000 = 8 x 125), M-fastest decode (MT = 8)
    const int nwg = gridDim.x;
    int swz = (blockIdx.x & 7) * (nwg >> 3) + (blockIdx.x >> 3);
    const int mt = swz & 7;
    const int nt = swz >> 3;
    const int m0 = mt * 256, n0 = nt * 256;

    // staging: thread t covers row (t>>3) of a 64-row segment, source chunk XOR (row&7)
    const int trow = tid >> 3;                        // 0..63
    const int tchk = (tid & 7) ^ (trow & 7);
    const ushort_t* gA = A + (size_t)(m0 + trow) * K + tchk * 8;
    const ushort_t* gW = W + (size_t)(n0 + trow) * K + tchk * 8;

    const int lr = lane & 15;
    const int lg = lane >> 4;
    const int wm = (w >> 2) * 128;                    // 2 M-wave rows
    const int wn = (w & 3) * 64;                      // 4 N-wave cols

    f32x4 acc[8][4] = {};

    auto stage = [&](int buf, int k0) {
        #pragma unroll
        for (int seg = 0; seg < 4; ++seg) {           // rows seg*64 .. seg*64+63
            gl_lds16(gA + (size_t)(seg * 64) * K + k0, &Ls[buf][0][seg * 4096 + w * 512]);
            gl_lds16(gW + (size_t)(seg * 64) * K + k0, &Ls[buf][1][seg * 4096 + w * 512]);
        }
    };

    stage(0, 0);
    __syncthreads();
    int cur = 0;
    const int NT = K / 64;
    for (int t = 0; t < NT; ++t) {
        if (t + 1 < NT) stage(cur ^ 1, (t + 1) * 64);  // prefetch into other buffer
        const ushort_t* Ab = Ls[cur][0];
        const ushort_t* Bb = Ls[cur][1];
        bf16x8 bv[4][2];
        #pragma unroll
        for (int nf = 0; nf < 4; ++nf) {
            int rr = wn + nf * 16 + lr;
            #pragma unroll
            for (int kk = 0; kk < 2; ++kk) {
                int ch = (kk * 4 + lg) ^ (rr & 7);
                bv[nf][kk] = *(const bf16x8*)&Bb[rr * 64 + ch * 8];
            }
        }
        __builtin_amdgcn_s_setprio(1);
        #pragma unroll
        for (int mf = 0; mf < 8; ++mf) {
            int rr = wm + mf * 16 + lr;
            int ch0 = lg ^ (rr & 7);
            int ch1 = (4 + lg) ^ (rr & 7);
            bf16x8 a0 = *(const bf16x8*)&Ab[rr * 64 + ch0 * 8];
            bf16x8 a1 = *(const bf16x8*)&Ab[rr * 64 + ch1 * 8];
            #pragma unroll
            for (int nf = 0; nf < 4; ++nf) {
                acc[mf][nf] = __builtin_amdgcn_mfma_f32_16x16x32_bf16(a0, bv[nf][0], acc[mf][nf], 0, 0, 0);
                acc[mf][nf] = __builtin_amdgcn_mfma_f32_16x16x32_bf16(a1, bv[nf][1], acc[mf][nf], 0, 0, 0);
            }
        }
        __builtin_amdgcn_s_setprio(0);
        __syncthreads();                               // drains prefetch + ends read phase
        cur ^= 1;
    }

    const int rbase = lg * 4;
    #pragma unroll
    for (int mf = 0; mf < 8; ++mf) {
        #pragma unroll
        for (int nf = 0; nf < 4; ++nf) {
            #pragma unroll
            for (int r = 0; r < 4; ++r) {
                int row = m0 + wm + mf * 16 + rbase + r;
                int col = n0 + wn + nf * 16 + lr;
                C[(size_t)row * N + col] = acc[mf][nf][r];
            }
        }
    }
}

// ---------------- MFMA flash attention, no-LDS K/V (L2-resident), 1 wave / 16 q-rows ----------------
__global__ __launch_bounds__(64) void attn_mfma(const ushort_t* __restrict__ qkv,
    const ushort_t* __restrict__ vt, ushort_t* __restrict__ o)
{
    __shared__ ushort_t Ps[16 * 136];

    // bh-clustered XCD swizzle: 1536 blocks -> 8 chunks of 192 (3 bh each)
    int swz = (blockIdx.x & 7) * 192 + (blockIdx.x >> 3);
    const int bh  = swz >> 6;
    const int qtl = 63 - (swz & 63);     // heavy q-tiles first within chunk
    const int b   = bh / H_;
    const int h   = bh % H_;
    const int lane = threadIdx.x;
    const int l15  = lane & 15;
    const int lg   = lane >> 4;
    const int qbase = qtl * 16;
    const int qlast = qbase + 15;

    const ushort_t* qp = qkv + ((size_t)(b * T_) + qbase + l15) * 2304 + h * 64 + lg * 8;
    bf16x8 qf0 = *(const bf16x8*)qp;
    bf16x8 qf1 = *(const bf16x8*)(qp + 32);

    f32x4 od[4] = {};
    float mr[4] = {-INFINITY, -INFINITY, -INFINITY, -INFINITY};
    float lr[4] = {0.f, 0.f, 0.f, 0.f};

    const ushort_t* kbase = qkv + (size_t)(b * T_) * 2304 + 768 + h * 64;
    const ushort_t* vbase = vt + (size_t)bh * 64 * T_;
    const float SC = 0.18033688011112042f;   // 0.125 * log2(e): softmax in exp2 domain

    for (int j0 = 0; j0 <= qlast; j0 += 128) {
        f32x4 s[8];
        __builtin_amdgcn_s_setprio(1);
        #pragma unroll
        for (int n = 0; n < 8; ++n) {
            if (j0 + 16 * n <= qlast) {
                const ushort_t* kr = kbase + (size_t)(j0 + 16 * n + l15) * 2304 + lg * 8;
                bf16x8 kf0 = *(const bf16x8*)kr;
                bf16x8 kf1 = *(const bf16x8*)(kr + 32);
                f32x4 a = {};
                a = __builtin_amdgcn_mfma_f32_16x16x32_bf16(qf0, kf0, a, 0, 0, 0);
                a = __builtin_amdgcn_mfma_f32_16x16x32_bf16(qf1, kf1, a, 0, 0, 0);
                s[n] = a;
            } else {
                s[n] = f32x4{-INFINITY, -INFINITY, -INFINITY, -INFINITY};
            }
        }
        __builtin_amdgcn_s_setprio(0);

        #pragma unroll
        for (int n = 0; n < 8; ++n) {
            #pragma unroll
            for (int r = 0; r < 4; ++r) {
                float v = s[n][r] * SC;
                int jg = j0 + 16 * n + l15;
                int qg = qbase + lg * 4 + r;
                if (jg > qg) v = -INFINITY;
                s[n][r] = v;
            }
        }

        float al[4];
        #pragma unroll
        for (int r = 0; r < 4; ++r) {
            float tm = fmaxf(fmaxf(fmaxf(s[0][r], s[1][r]), fmaxf(s[2][r], s[3][r])),
                             fmaxf(fmaxf(s[4][r], s[5][r]), fmaxf(s[6][r], s[7][r])));
            tm = fmaxf(tm, __shfl_xor(tm, 1, 64));
            tm = fmaxf(tm, __shfl_xor(tm, 2, 64));
            tm = fmaxf(tm, __shfl_xor(tm, 4, 64));
            tm = fmaxf(tm, __shfl_xor(tm, 8, 64));
            float mn = fmaxf(mr[r], tm);
            al[r] = exp2f(mr[r] - mn);
            mr[r] = mn;
        }
        #pragma unroll
        for (int n = 0; n < 8; ++n)
            #pragma unroll
            for (int r = 0; r < 4; ++r)
                s[n][r] = exp2f(s[n][r] - mr[r]);
        #pragma unroll
        for (int r = 0; r < 4; ++r) {
            float ps = (s[0][r] + s[1][r]) + (s[2][r] + s[3][r]);
            ps += (s[4][r] + s[5][r]) + (s[6][r] + s[7][r]);
            ps += __shfl_xor(ps, 1, 64);
            ps += __shfl_xor(ps, 2, 64);
            ps += __shfl_xor(ps, 4, 64);
            ps += __shfl_xor(ps, 8, 64);
            lr[r] = lr[r] * al[r] + ps;
        }
        #pragma unroll
        for (int n = 0; n < 4; ++n)
            #pragma unroll
            for (int r = 0; r < 4; ++r)
                od[n][r] *= al[r];

        // P -> LDS rows (q = lg*4+r, j fast) for the PV A-fragment
        #pragma unroll
        for (int n = 0; n < 8; ++n)
            #pragma unroll
            for (int r = 0; r < 4; ++r)
                Ps[(lg * 4 + r) * 136 + 16 * n + l15] = (ushort_t)f2bf1(s[n][r]);

        __builtin_amdgcn_s_setprio(1);
        #pragma unroll
        for (int kc = 0; kc < 4; ++kc) {
            if (j0 + kc * 32 <= qlast) {
                bf16x8 pa = *(const bf16x8*)&Ps[l15 * 136 + kc * 32 + lg * 8];
                #pragma unroll
                for (int nn = 0; nn < 4; ++nn) {
                    bf16x8 vf = *(const bf16x8*)&vbase[(size_t)(16 * nn + l15) * T_ + j0 + kc * 32 + lg * 8];
                    od[nn] = __builtin_amdgcn_mfma_f32_16x16x32_bf16(pa, vf, od[nn], 0, 0, 0);
                }
            }
        }
        __builtin_amdgcn_s_setprio(0);
    }

    #pragma unroll
    for (int r = 0; r < 4; ++r) {
        float inv = 1.0f / lr[r];
        int row = qbase + lg * 4 + r;
        ushort_t* op = o + ((size_t)(b * T_ + row)) * 768 + h * 64 + l15;
        #pragma unroll
        for (int nn = 0; nn < 4; ++nn)
            op[16 * nn] = (ushort_t)f2bf1(od[nn][r] * inv);
    }
}

// ---------------- LN core (shared) ----------------
__device__ __forceinline__ void ln_body(float v0, float v1, float v2,
    const float* __restrict__ w, const float* __restrict__ bia,
    ushort_t* __restrict__ orow, int tid)
{
    float s  = v0 + v1 + v2;
    float s2 = v0 * v0 + v1 * v1 + v2 * v2;
    #pragma unroll
    for (int off = 32; off > 0; off >>= 1) {
        s  += __shfl_down(s,  off, 64);
        s2 += __shfl_down(s2, off, 64);
    }
    __shared__ float sh[8];
    const int wave = tid >> 6;
    if ((tid & 63) == 0) { sh[wave] = s; sh[4 + wave] = s2; }
    __syncthreads();
    float S  = sh[0] + sh[1] + sh[2] + sh[3];
    float S2 = sh[4] + sh[5] + sh[6] + sh[7];
    float mean = S * (1.f / 768.f);
    float var  = S2 * (1.f / 768.f) - mean * mean;
    float inv  = rsqrtf(var + 1e-5f);
    orow[tid]       = (ushort_t)f2bf1((v0 - mean) * inv * w[tid]       + bia[tid]);
    orow[tid + 256] = (ushort_t)f2bf1((v1 - mean) * inv * w[tid + 256] + bia[tid + 256]);
    orow[tid + 512] = (ushort_t)f2bf1((v2 - mean) * inv * w[tid + 512] + bia[tid + 512]);
}

// ---------------- fused: x += P0+P1+P2+P3 (bf16 partials) ; h = LN(x) ----------------
__global__ __launch_bounds__(256) void ln_red4(float* __restrict__ x,
    const ushort_t* __restrict__ P, const float* __restrict__ w,
    const float* __restrict__ bia, ushort_t* __restrict__ out)
{
    const int row = blockIdx.x;
    const int tid = threadIdx.x;
    const size_t base = (size_t)row * 768;
    const size_t st = (size_t)BT_ * D_;
    float v0 = x[base + tid];
    float v1 = x[base + tid + 256];
    float v2 = x[base + tid + 512];
    #pragma unroll
    for (int p = 0; p < 4; ++p) {
        v0 += bf2f(P[p * st + base + tid]);
        v1 += bf2f(P[p * st + base + tid + 256]);
        v2 += bf2f(P[p * st + base + tid + 512]);
    }
    x[base + tid]       = v0;
    x[base + tid + 256] = v1;
    x[base + tid + 512] = v2;
    ln_body(v0, v1, v2, w, bia, out + base, tid);
}

// ---------------- fused embedding + first LN ----------------
__global__ __launch_bounds__(256) void embed_ln(const int* __restrict__ ids,
    const float* __restrict__ tok, const float* __restrict__ pos,
    const float* __restrict__ w, const float* __restrict__ bia,
    float* __restrict__ x, ushort_t* __restrict__ out)
{
    const int bt = blockIdx.x;
    const int t  = bt % T_;
    const int id = ids[bt];
    const int tid = threadIdx.x;
    const float* tr = tok + (size_t)id * 768;
    const float* pr = pos + (size_t)t * 768;
    const size_t base = (size_t)bt * 768;
    float v0 = tr[tid]       + pr[tid];
    float v1 = tr[tid + 256] + pr[tid + 256];
    float v2 = tr[tid + 512] + pr[tid + 512];
    x[base + tid]       = v0;
    x[base + tid + 256] = v1;
    x[base + tid + 512] = v2;
    ln_body(v0, v1, v2, w, bia, out + base, tid);
}

// ---------------- launcher ----------------
extern "C" void kernel_launch(void* const* d_in, const int* in_sizes, int n_in,
                              void* d_out, int out_size, void* d_ws, size_t ws_size,
                              hipStream_t stream)
{
    const int*   ids   = (const int*)  d_in[0];
    const float* tok   = (const float*)d_in[1];
    const float* pos   = (const float*)d_in[2];
    const float* ln1w  = (const float*)d_in[3];
    const float* ln1b  = (const float*)d_in[4];
    const float* qkvw  = (const float*)d_in[5];
    const float* outw  = (const float*)d_in[6];
    const float* ln2w  = (const float*)d_in[7];
    const float* ln2b  = (const float*)d_in[8];
    const float* upw   = (const float*)d_in[9];
    const float* downw = (const float*)d_in[10];
    const float* lnfw  = (const float*)d_in[11];
    const float* lnfb  = (const float*)d_in[12];
    float* out = (float*)d_out;

    // workspace layout (~130 MB of ~1 GiB d_ws)
    char* ws = (char*)d_ws;
    ushort_t* h    = (ushort_t*)ws;                               //  3,145,728 B
    float*    x    = (float*)   (ws + 3145728);                   //  6,291,456 B
    ushort_t* qkv  = (ushort_t*)(ws + 9437184);                   //  9,437,184 B
    ushort_t* o    = qkv  + (size_t)BT_ * 3 * D_;                 //  3,145,728 B
    ushort_t* vt   = o    + (size_t)BT_ * D_;                     //  3,145,728 B
    ushort_t* ffh  = vt   + (size_t)B_ * H_ * 64 * T_;            // 12,582,912 B
    ushort_t* P4   = (ushort_t*)(ws + 37748736);                  // 12,582,912 B (4 bf16 partials)
    ushort_t* layerW = (ushort_t*)(ws + 50331648);                // 14,155,776 B
    ushort_t* tokW   = (ushort_t*)(ws + 67108864);                // 49,152,000 B

    ushort_t* qkvwB  = layerW;
    ushort_t* outwB  = qkvwB + (size_t)3 * D_ * D_;
    ushort_t* upwB   = outwB + (size_t)D_ * D_;
    ushort_t* downwB = upwB  + (size_t)FF_ * D_;

    for (int l = 0; l < L_; ++l) {
        // per-layer weight cast: this layer's weights land L2/L3-warm for the GEMMs below
        cast_layer<<<1024, 256, 0, stream>>>(
            qkvw  + (size_t)l * 3 * D_ * D_,
            outw  + (size_t)l * D_ * D_,
            upw   + (size_t)l * FF_ * D_,
            downw + (size_t)l * D_ * FF_, layerW);

        if (l == 0)
            embed_ln<<<BT_, 256, 0, stream>>>(ids, tok, pos, ln1w, ln1b, x, h);
        else
            ln_red4<<<BT_, 256, 0, stream>>>(x, P4, ln1w + l * D_, ln1b + l * D_, h);

        // QKV GEMM with fused V-transpose epilogue (BM=64: grid 576)
        gemm_bt<EPI_QKV, 64, 1><<<32 * (3 * D_ / 128), 256, 0, stream>>>(
            h, qkvwB, nullptr, qkv, vt, 3 * D_, D_, D_);

        attn_mfma<<<B_ * H_ * (T_ / 16), 64, 0, stream>>>(qkv, vt, o);

        // out-proj: split-K KS=4 (grid 768), bf16 partials -> P4
        gemm_bt<EPI_PART, 64, 4><<<32 * (D_ / 128) * 4, 256, 0, stream>>>(
            o, outwB, nullptr, P4, nullptr, D_, D_, D_ / 4);

        ln_red4<<<BT_, 256, 0, stream>>>(x, P4, ln2w + l * D_, ln2b + l * D_, h);

        gemm_bt<EPI_GELU, 64, 1><<<32 * (FF_ / 128), 256, 0, stream>>>(
            h, upwB, nullptr, ffh, nullptr, FF_, D_, D_);

        // down-proj: split-K KS=4 (grid 768), bf16 partials -> P4
        gemm_bt<EPI_PART, 64, 4><<<32 * (D_ / 128) * 4, 256, 0, stream>>>(
            ffh, downwB, nullptr, P4, nullptr, D_, FF_, FF_ / 4);
    }

    ln_red4<<<BT_, 256, 0, stream>>>(x, P4, lnfw, lnfb, h);

    cast_bf16<<<2048, 256, 0, stream>>>(tok, tokW, V_ * D_ / 8);
    gemm256<<<(2048 / 256) * (V_ / 256), 512, 0, stream>>>(h, tokW, out, V_, D_);
}

// Round 14
// 1820.769 us; speedup vs baseline: 1.1216x; 1.0595x over previous
//
#include <hip/hip_runtime.h>
#include <hip/hip_bf16.h>
#include <math.h>

#define L_  12
#define H_  12
#define D_  768
#define FF_ 3072
#define V_  32000
#define T_  1024
#define B_  2
#define BT_ (B_*T_)

typedef unsigned short ushort_t;
typedef unsigned int   uint_t;
typedef __bf16 bf16x8 __attribute__((ext_vector_type(8)));
typedef float  f32x4  __attribute__((ext_vector_type(4)));

__device__ __forceinline__ uint_t f2bf1(float f) {
    uint_t u = __builtin_bit_cast(uint_t, f);
    return (u + 0x7FFFu + ((u >> 16) & 1u)) >> 16;   // RNE truncate to bf16
}
__device__ __forceinline__ uint_t f2bf2(float lo, float hi) {
    return f2bf1(lo) | (f2bf1(hi) << 16);
}
__device__ __forceinline__ float bf2f(ushort_t u) {
    return __builtin_bit_cast(float, (uint_t)u << 16);
}

__device__ __forceinline__ void gl_lds16(const ushort_t* g, ushort_t* l) {
    __builtin_amdgcn_global_load_lds(
        (const __attribute__((address_space(1))) uint_t*)g,
        (__attribute__((address_space(3))) uint_t*)l, 16, 0, 0);
}

// ---------------- weight cast ----------------
__global__ __launch_bounds__(256) void cast_bf16(const float* __restrict__ in,
                                                 ushort_t* __restrict__ out, int n8)
{
    for (int i = blockIdx.x * 256 + threadIdx.x; i < n8; i += gridDim.x * 256) {
        const float4* p = (const float4*)(in + (size_t)i * 8);
        float4 a = p[0], b = p[1];
        *(uint4*)(out + (size_t)i * 8) =
            make_uint4(f2bf2(a.x,a.y), f2bf2(a.z,a.w), f2bf2(b.x,b.y), f2bf2(b.z,b.w));
    }
}

// cast one layer's {qkv_w, out_w, up_w, down_w} -> contiguous bf16 (device body, shared)
__device__ __forceinline__ void cast_body(const float* __restrict__ q,
    const float* __restrict__ o, const float* __restrict__ u, const float* __restrict__ d,
    ushort_t* __restrict__ out, int bid, int nb)
{
    const int N0 = 3*D_*D_/8, N1 = N0 + D_*D_/8, N2 = N1 + FF_*D_/8, N3 = N2 + D_*FF_/8;
    for (int i = bid * 256 + threadIdx.x; i < N3; i += nb * 256) {
        const float* src;
        if      (i < N0) src = q + (size_t)i * 8;
        else if (i < N1) src = o + (size_t)(i - N0) * 8;
        else if (i < N2) src = u + (size_t)(i - N1) * 8;
        else             src = d + (size_t)(i - N2) * 8;
        const float4* p = (const float4*)src;
        float4 a = p[0], b = p[1];
        *(uint4*)(out + (size_t)i * 8) =
            make_uint4(f2bf2(a.x,a.y), f2bf2(a.z,a.w), f2bf2(b.x,b.y), f2bf2(b.z,b.w));
    }
}

// ---------------- GEMM: C[M,N] = A[M,K] @ W[N,K]^T, bf16, BK=64, dbuf ----------------
#define EPI_F32   0
#define EPI_BF16  1
#define EPI_GELU  2
#define EPI_PART  3   // split-K bf16 partials: slice ks -> (ushort*)Cv + ks*BT_*D_
#define EPI_QKV   4   // Q,K -> Cv (bf16, stride 2304); V -> Vt transposed [bh][64][T]

template <int EPI, int BM, int KS>
__global__ __launch_bounds__(256) void gemm_bt(
    const ushort_t* __restrict__ A, const ushort_t* __restrict__ W,
    void* Cv, ushort_t* __restrict__ Vt, int N, int K, int Kc)
{
    constexpr int MI = BM / 32;          // A-fragment tiles per wave
    constexpr int AH = BM * 64;          // ushorts per A buffer (BK=64)
    constexpr int BH = 128 * 64;
    __shared__ ushort_t As[2 * AH];      // linear dest (global_load_lds); content chunk-swizzled
    __shared__ ushort_t Bs[2 * BH];

    const int tid  = threadIdx.x;
    const int w    = tid >> 6;
    const int lane = tid & 63;

    // XCD-aware swizzle (nwg % 8 == 0 for all our shapes), M-fastest decode
    const int nwg = gridDim.x;
    int swz = (blockIdx.x & 7) * (nwg >> 3) + (blockIdx.x >> 3);
    constexpr int MT = 2048 / BM;
    const int mt = swz & (MT - 1);
    int rest     = swz / MT;
    const int ks = rest & (KS - 1);
    const int nt = rest / KS;
    const int m0 = mt * BM, n0 = nt * 128;
    const int kb = ks * Kc;

    // staging: 8-row issues; source col chunk XOR'd with (row & 7) so the
    // LINEAR lds write lands swizzled (r5-validated layout)
    const int srow = lane >> 3;                       // 0..7
    const int scol = ((lane & 7) ^ srow) * 8;
    const ushort_t* gA = A + (size_t)(m0 + w * (BM / 4) + srow) * K + scol;
    const ushort_t* gW = W + (size_t)(n0 + w * 32 + srow) * K + scol;
    const size_t row8 = (size_t)8 * K;

    const int lr = lane & 15;
    const int lg = lane >> 4;
    const int wm = (w >> 1) * (BM / 2);
    const int wn = (w & 1) * 64;

    f32x4 acc[MI][4] = {};

    auto stage = [&](int buf, int k0) {
        ushort_t* lA = As + buf * AH + w * (BM / 4) * 64;
        ushort_t* lB = Bs + buf * BH + w * 2048;
        #pragma unroll
        for (int i = 0; i < BM / 32; ++i)
            gl_lds16(gA + k0 + i * row8, lA + i * 512);
        #pragma unroll
        for (int i = 0; i < 4; ++i)
            gl_lds16(gW + k0 + i * row8, lB + i * 512);
    };

    stage(0, kb);
    __syncthreads();
    int cur = 0;
    for (int k0 = kb; k0 < kb + Kc; k0 += 64) {
        if (k0 + 64 < kb + Kc) stage(cur ^ 1, k0 + 64);   // prefetch flies under MFMA below
        const ushort_t* Ab = As + cur * AH;
        const ushort_t* Bb = Bs + cur * BH;
        __builtin_amdgcn_s_setprio(1);
        #pragma unroll
        for (int kk = 0; kk < 2; ++kk) {
            bf16x8 av[MI], bv[4];
            #pragma unroll
            for (int i = 0; i < MI; ++i) {
                int rr = wm + i * 16 + lr;
                int ch = (lg + 4 * kk) ^ (rr & 7);
                av[i] = *(const bf16x8*)&Ab[rr * 64 + ch * 8];
            }
            #pragma unroll
            for (int j = 0; j < 4; ++j) {
                int rr = wn + j * 16 + lr;
                int ch = (lg + 4 * kk) ^ (rr & 7);
                bv[j] = *(const bf16x8*)&Bb[rr * 64 + ch * 8];
            }
            #pragma unroll
            for (int i = 0; i < MI; ++i)
                #pragma unroll
                for (int j = 0; j < 4; ++j)
                    acc[i][j] = __builtin_amdgcn_mfma_f32_16x16x32_bf16(av[i], bv[j], acc[i][j], 0, 0, 0);
        }
        __builtin_amdgcn_s_setprio(0);
        __syncthreads();                               // drains prefetch + ends read phase
        cur ^= 1;
    }

    float*    Cf = (float*)Cv;
    ushort_t* Cb = (ushort_t*)Cv;
    ushort_t* Pp = (EPI == EPI_PART) ? ((ushort_t*)Cv + (size_t)ks * BT_ * D_) : nullptr;
    const int rbase = lg * 4;
    #pragma unroll
    for (int i = 0; i < MI; ++i) {
        #pragma unroll
        for (int j = 0; j < 4; ++j) {
            const int row0 = m0 + wm + i * 16 + rbase;
            const int col  = n0 + wn + j * 16 + lr;
            if (EPI == EPI_QKV) {
                if (col < 1536) {              // Q or K: bf16 into qkv (wave-uniform branch)
                    #pragma unroll
                    for (int r = 0; r < 4; ++r)
                        Cb[(size_t)(row0 + r) * 2304 + col] = (ushort_t)f2bf1(acc[i][j][r]);
                } else {                       // V: transposed into vt[bh][64][T], 4 t's per store
                    const int hh = (col - 1536) >> 6, dd = (col - 1536) & 63;
                    const int bb = row0 >> 10,        tt = row0 & 1023;
                    uint2 pk;
                    pk.x = f2bf2(acc[i][j][0], acc[i][j][1]);
                    pk.y = f2bf2(acc[i][j][2], acc[i][j][3]);
                    *(uint2*)&Vt[(((size_t)bb * H_ + hh) * 64 + dd) * T_ + tt] = pk;
                }
            } else {
                #pragma unroll
                for (int r = 0; r < 4; ++r) {
                    size_t idx = (size_t)(row0 + r) * N + col;
                    float v = acc[i][j][r];
                    if (EPI == EPI_F32)  Cf[idx] = v;
                    if (EPI == EPI_BF16) Cb[idx] = (ushort_t)f2bf1(v);
                    if (EPI == EPI_GELU) Cb[idx] = (ushort_t)f2bf1(0.5f * v * (1.0f + erff(v * 0.70710678118654752f)));
                    if (EPI == EPI_PART) Pp[idx] = (ushort_t)f2bf1(v);
                }
            }
        }
    }
}

// ---------------- lm_head GEMM: 256x256 tile, 8 waves, BK=64, dbuf, 64 MFMA/wave/barrier ----------------
__global__ __launch_bounds__(512, 2) void gemm256(
    const ushort_t* __restrict__ A, const ushort_t* __restrict__ W,
    float* __restrict__ C, int N, int K)
{
    __shared__ ushort_t Ls[2][2][256 * 64];   // [buf][A=0/B=1][256 rows x 64 k] = 128 KiB

    const int tid  = threadIdx.x;
    const int w    = tid >> 6;
    const int lane = tid & 63;

    // XCD swizzle (grid 1000 = 8 x 125), M-fastest decode (MT = 8)
    const int nwg = gridDim.x;
    int swz = (blockIdx.x & 7) * (nwg >> 3) + (blockIdx.x >> 3);
    const int mt = swz & 7;
    const int nt = swz >> 3;
    const int m0 = mt * 256, n0 = nt * 256;

    // staging: thread t covers row (t>>3) of a 64-row segment, source chunk XOR (row&7)
    const int trow = tid >> 3;                        // 0..63
    const int tchk = (tid & 7) ^ (trow & 7);
    const ushort_t* gA = A + (size_t)(m0 + trow) * K + tchk * 8;
    const ushort_t* gW = W + (size_t)(n0 + trow) * K + tchk * 8;

    const int lr = lane & 15;
    const int lg = lane >> 4;
    const int wm = (w >> 2) * 128;                    // 2 M-wave rows
    const int wn = (w & 3) * 64;                      // 4 N-wave cols

    f32x4 acc[8][4] = {};

    auto stage = [&](int buf, int k0) {
        #pragma unroll
        for (int seg = 0; seg < 4; ++seg) {           // rows seg*64 .. seg*64+63
            gl_lds16(gA + (size_t)(seg * 64) * K + k0, &Ls[buf][0][seg * 4096 + w * 512]);
            gl_lds16(gW + (size_t)(seg * 64) * K + k0, &Ls[buf][1][seg * 4096 + w * 512]);
        }
    };

    stage(0, 0);
    __syncthreads();
    int cur = 0;
    const int NT = K / 64;
    for (int t = 0; t < NT; ++t) {
        if (t + 1 < NT) stage(cur ^ 1, (t + 1) * 64);  // prefetch into other buffer
        const ushort_t* Ab = Ls[cur][0];
        const ushort_t* Bb = Ls[cur][1];
        bf16x8 bv[4][2];
        #pragma unroll
        for (int nf = 0; nf < 4; ++nf) {
            int rr = wn + nf * 16 + lr;
            #pragma unroll
            for (int kk = 0; kk < 2; ++kk) {
                int ch = (kk * 4 + lg) ^ (rr & 7);
                bv[nf][kk] = *(const bf16x8*)&Bb[rr * 64 + ch * 8];
            }
        }
        __builtin_amdgcn_s_setprio(1);
        #pragma unroll
        for (int mf = 0; mf < 8; ++mf) {
            int rr = wm + mf * 16 + lr;
            int ch0 = lg ^ (rr & 7);
            int ch1 = (4 + lg) ^ (rr & 7);
            bf16x8 a0 = *(const bf16x8*)&Ab[rr * 64 + ch0 * 8];
            bf16x8 a1 = *(const bf16x8*)&Ab[rr * 64 + ch1 * 8];
            #pragma unroll
            for (int nf = 0; nf < 4; ++nf) {
                acc[mf][nf] = __builtin_amdgcn_mfma_f32_16x16x32_bf16(a0, bv[nf][0], acc[mf][nf], 0, 0, 0);
                acc[mf][nf] = __builtin_amdgcn_mfma_f32_16x16x32_bf16(a1, bv[nf][1], acc[mf][nf], 0, 0, 0);
            }
        }
        __builtin_amdgcn_s_setprio(0);
        __syncthreads();                               // drains prefetch + ends read phase
        cur ^= 1;
    }

    const int rbase = lg * 4;
    #pragma unroll
    for (int mf = 0; mf < 8; ++mf) {
        #pragma unroll
        for (int nf = 0; nf < 4; ++nf) {
            #pragma unroll
            for (int r = 0; r < 4; ++r) {
                int row = m0 + wm + mf * 16 + rbase + r;
                int col = n0 + wn + nf * 16 + lr;
                C[(size_t)row * N + col] = acc[mf][nf][r];
            }
        }
    }
}

// ---------------- MFMA flash attention, no-LDS K/V (L2-resident), 1 wave / 16 q-rows ----------------
__global__ __launch_bounds__(64) void attn_mfma(const ushort_t* __restrict__ qkv,
    const ushort_t* __restrict__ vt, ushort_t* __restrict__ o)
{
    __shared__ ushort_t Ps[16 * 136];

    // bh-clustered XCD swizzle: 1536 blocks -> 8 chunks of 192 (3 bh each)
    int swz = (blockIdx.x & 7) * 192 + (blockIdx.x >> 3);
    const int bh  = swz >> 6;
    const int qtl = 63 - (swz & 63);     // heavy q-tiles first within chunk
    const int b   = bh / H_;
    const int h   = bh % H_;
    const int lane = threadIdx.x;
    const int l15  = lane & 15;
    const int lg   = lane >> 4;
    const int qbase = qtl * 16;
    const int qlast = qbase + 15;

    const ushort_t* qp = qkv + ((size_t)(b * T_) + qbase + l15) * 2304 + h * 64 + lg * 8;
    bf16x8 qf0 = *(const bf16x8*)qp;
    bf16x8 qf1 = *(const bf16x8*)(qp + 32);

    f32x4 od[4] = {};
    float mr[4] = {-INFINITY, -INFINITY, -INFINITY, -INFINITY};
    float lr[4] = {0.f, 0.f, 0.f, 0.f};

    const ushort_t* kbase = qkv + (size_t)(b * T_) * 2304 + 768 + h * 64;
    const ushort_t* vbase = vt + (size_t)bh * 64 * T_;
    const float SC = 0.18033688011112042f;   // 0.125 * log2(e): softmax in exp2 domain

    for (int j0 = 0; j0 <= qlast; j0 += 128) {
        f32x4 s[8];
        __builtin_amdgcn_s_setprio(1);
        #pragma unroll
        for (int n = 0; n < 8; ++n) {
            if (j0 + 16 * n <= qlast) {
                const ushort_t* kr = kbase + (size_t)(j0 + 16 * n + l15) * 2304 + lg * 8;
                bf16x8 kf0 = *(const bf16x8*)kr;
                bf16x8 kf1 = *(const bf16x8*)(kr + 32);
                f32x4 a = {};
                a = __builtin_amdgcn_mfma_f32_16x16x32_bf16(qf0, kf0, a, 0, 0, 0);
                a = __builtin_amdgcn_mfma_f32_16x16x32_bf16(qf1, kf1, a, 0, 0, 0);
                s[n] = a;
            } else {
                s[n] = f32x4{-INFINITY, -INFINITY, -INFINITY, -INFINITY};
            }
        }
        __builtin_amdgcn_s_setprio(0);

        #pragma unroll
        for (int n = 0; n < 8; ++n) {
            #pragma unroll
            for (int r = 0; r < 4; ++r) {
                float v = s[n][r] * SC;
                int jg = j0 + 16 * n + l15;
                int qg = qbase + lg * 4 + r;
                if (jg > qg) v = -INFINITY;
                s[n][r] = v;
            }
        }

        float al[4];
        #pragma unroll
        for (int r = 0; r < 4; ++r) {
            float tm = fmaxf(fmaxf(fmaxf(s[0][r], s[1][r]), fmaxf(s[2][r], s[3][r])),
                             fmaxf(fmaxf(s[4][r], s[5][r]), fmaxf(s[6][r], s[7][r])));
            tm = fmaxf(tm, __shfl_xor(tm, 1, 64));
            tm = fmaxf(tm, __shfl_xor(tm, 2, 64));
            tm = fmaxf(tm, __shfl_xor(tm, 4, 64));
            tm = fmaxf(tm, __shfl_xor(tm, 8, 64));
            float mn = fmaxf(mr[r], tm);
            al[r] = exp2f(mr[r] - mn);
            mr[r] = mn;
        }
        #pragma unroll
        for (int n = 0; n < 8; ++n)
            #pragma unroll
            for (int r = 0; r < 4; ++r)
                s[n][r] = exp2f(s[n][r] - mr[r]);
        #pragma unroll
        for (int r = 0; r < 4; ++r) {
            float ps = (s[0][r] + s[1][r]) + (s[2][r] + s[3][r]);
            ps += (s[4][r] + s[5][r]) + (s[6][r] + s[7][r]);
            ps += __shfl_xor(ps, 1, 64);
            ps += __shfl_xor(ps, 2, 64);
            ps += __shfl_xor(ps, 4, 64);
            ps += __shfl_xor(ps, 8, 64);
            lr[r] = lr[r] * al[r] + ps;
        }
        #pragma unroll
        for (int n = 0; n < 4; ++n)
            #pragma unroll
            for (int r = 0; r < 4; ++r)
                od[n][r] *= al[r];

        // P -> LDS rows (q = lg*4+r, j fast) for the PV A-fragment
        #pragma unroll
        for (int n = 0; n < 8; ++n)
            #pragma unroll
            for (int r = 0; r < 4; ++r)
                Ps[(lg * 4 + r) * 136 + 16 * n + l15] = (ushort_t)f2bf1(s[n][r]);

        __builtin_amdgcn_s_setprio(1);
        #pragma unroll
        for (int kc = 0; kc < 4; ++kc) {
            if (j0 + kc * 32 <= qlast) {
                bf16x8 pa = *(const bf16x8*)&Ps[l15 * 136 + kc * 32 + lg * 8];
                #pragma unroll
                for (int nn = 0; nn < 4; ++nn) {
                    bf16x8 vf = *(const bf16x8*)&vbase[(size_t)(16 * nn + l15) * T_ + j0 + kc * 32 + lg * 8];
                    od[nn] = __builtin_amdgcn_mfma_f32_16x16x32_bf16(pa, vf, od[nn], 0, 0, 0);
                }
            }
        }
        __builtin_amdgcn_s_setprio(0);
    }

    #pragma unroll
    for (int r = 0; r < 4; ++r) {
        float inv = 1.0f / lr[r];
        int row = qbase + lg * 4 + r;
        ushort_t* op = o + ((size_t)(b * T_ + row)) * 768 + h * 64 + l15;
        #pragma unroll
        for (int nn = 0; nn < 4; ++nn)
            op[16 * nn] = (ushort_t)f2bf1(od[nn][r] * inv);
    }
}

// ---------------- LN core (shared) ----------------
__device__ __forceinline__ void ln_body(float v0, float v1, float v2,
    const float* __restrict__ w, const float* __restrict__ bia,
    ushort_t* __restrict__ orow, int tid)
{
    float s  = v0 + v1 + v2;
    float s2 = v0 * v0 + v1 * v1 + v2 * v2;
    #pragma unroll
    for (int off = 32; off > 0; off >>= 1) {
        s  += __shfl_down(s,  off, 64);
        s2 += __shfl_down(s2, off, 64);
    }
    __shared__ float sh[8];
    const int wave = tid >> 6;
    if ((tid & 63) == 0) { sh[wave] = s; sh[4 + wave] = s2; }
    __syncthreads();
    float S  = sh[0] + sh[1] + sh[2] + sh[3];
    float S2 = sh[4] + sh[5] + sh[6] + sh[7];
    float mean = S * (1.f / 768.f);
    float var  = S2 * (1.f / 768.f) - mean * mean;
    float inv  = rsqrtf(var + 1e-5f);
    orow[tid]       = (ushort_t)f2bf1((v0 - mean) * inv * w[tid]       + bia[tid]);
    orow[tid + 256] = (ushort_t)f2bf1((v1 - mean) * inv * w[tid + 256] + bia[tid + 256]);
    orow[tid + 512] = (ushort_t)f2bf1((v2 - mean) * inv * w[tid + 512] + bia[tid + 512]);
}

__device__ __forceinline__ void ln_red4_body(float* __restrict__ x,
    const ushort_t* __restrict__ P, const float* __restrict__ w,
    const float* __restrict__ bia, ushort_t* __restrict__ out, int row)
{
    const int tid = threadIdx.x;
    const size_t base = (size_t)row * 768;
    const size_t st = (size_t)BT_ * D_;
    float v0 = x[base + tid];
    float v1 = x[base + tid + 256];
    float v2 = x[base + tid + 512];
    #pragma unroll
    for (int p = 0; p < 4; ++p) {
        v0 += bf2f(P[p * st + base + tid]);
        v1 += bf2f(P[p * st + base + tid + 256]);
        v2 += bf2f(P[p * st + base + tid + 512]);
    }
    x[base + tid]       = v0;
    x[base + tid + 256] = v1;
    x[base + tid + 512] = v2;
    ln_body(v0, v1, v2, w, bia, out + base, tid);
}

// ---------------- fused: {x += P; h = LN(x)} for blocks<2048, weight-cast for the rest ----------------
__global__ __launch_bounds__(256) void ln_red4_cast(float* __restrict__ x,
    const ushort_t* __restrict__ P, const float* __restrict__ w,
    const float* __restrict__ bia, ushort_t* __restrict__ out,
    const float* __restrict__ cq, const float* __restrict__ co,
    const float* __restrict__ cu, const float* __restrict__ cd,
    ushort_t* __restrict__ wout)
{
    if (blockIdx.x < 2048)
        ln_red4_body(x, P, w, bia, out, blockIdx.x);
    else
        cast_body(cq, co, cu, cd, wout, blockIdx.x - 2048, 1024);
}

// plain ln_red4 (mid-layer and final)
__global__ __launch_bounds__(256) void ln_red4(float* __restrict__ x,
    const ushort_t* __restrict__ P, const float* __restrict__ w,
    const float* __restrict__ bia, ushort_t* __restrict__ out)
{
    ln_red4_body(x, P, w, bia, out, blockIdx.x);
}

// ---------------- fused embedding + first LN + layer-0 weight cast ----------------
__global__ __launch_bounds__(256) void embed_ln_cast(const int* __restrict__ ids,
    const float* __restrict__ tok, const float* __restrict__ pos,
    const float* __restrict__ w, const float* __restrict__ bia,
    float* __restrict__ x, ushort_t* __restrict__ out,
    const float* __restrict__ cq, const float* __restrict__ co,
    const float* __restrict__ cu, const float* __restrict__ cd,
    ushort_t* __restrict__ wout)
{
    if (blockIdx.x < 2048) {
        const int bt = blockIdx.x;
        const int t  = bt % T_;
        const int id = ids[bt];
        const int tid = threadIdx.x;
        const float* tr = tok + (size_t)id * 768;
        const float* pr = pos + (size_t)t * 768;
        const size_t base = (size_t)bt * 768;
        float v0 = tr[tid]       + pr[tid];
        float v1 = tr[tid + 256] + pr[tid + 256];
        float v2 = tr[tid + 512] + pr[tid + 512];
        x[base + tid]       = v0;
        x[base + tid + 256] = v1;
        x[base + tid + 512] = v2;
        ln_body(v0, v1, v2, w, bia, out + base, tid);
    } else {
        cast_body(cq, co, cu, cd, wout, blockIdx.x - 2048, 1024);
    }
}

// ---------------- launcher ----------------
extern "C" void kernel_launch(void* const* d_in, const int* in_sizes, int n_in,
                              void* d_out, int out_size, void* d_ws, size_t ws_size,
                              hipStream_t stream)
{
    const int*   ids   = (const int*)  d_in[0];
    const float* tok   = (const float*)d_in[1];
    const float* pos   = (const float*)d_in[2];
    const float* ln1w  = (const float*)d_in[3];
    const float* ln1b  = (const float*)d_in[4];
    const float* qkvw  = (const float*)d_in[5];
    const float* outw  = (const float*)d_in[6];
    const float* ln2w  = (const float*)d_in[7];
    const float* ln2b  = (const float*)d_in[8];
    const float* upw   = (const float*)d_in[9];
    const float* downw = (const float*)d_in[10];
    const float* lnfw  = (const float*)d_in[11];
    const float* lnfb  = (const float*)d_in[12];
    float* out = (float*)d_out;

    // workspace layout (~130 MB of ~1 GiB d_ws)
    char* ws = (char*)d_ws;
    ushort_t* h    = (ushort_t*)ws;                               //  3,145,728 B
    float*    x    = (float*)   (ws + 3145728);                   //  6,291,456 B
    ushort_t* qkv  = (ushort_t*)(ws + 9437184);                   //  9,437,184 B
    ushort_t* o    = qkv  + (size_t)BT_ * 3 * D_;                 //  3,145,728 B
    ushort_t* vt   = o    + (size_t)BT_ * D_;                     //  3,145,728 B
    ushort_t* ffh  = vt   + (size_t)B_ * H_ * 64 * T_;            // 12,582,912 B
    ushort_t* P4   = (ushort_t*)(ws + 37748736);                  // 12,582,912 B (4 bf16 partials)
    ushort_t* layerW = (ushort_t*)(ws + 50331648);                // 14,155,776 B
    ushort_t* tokW   = (ushort_t*)(ws + 67108864);                // 49,152,000 B

    ushort_t* qkvwB  = layerW;
    ushort_t* outwB  = qkvwB + (size_t)3 * D_ * D_;
    ushort_t* upwB   = outwB + (size_t)D_ * D_;
    ushort_t* downwB = upwB  + (size_t)FF_ * D_;

    for (int l = 0; l < L_; ++l) {
        const float* cq = qkvw  + (size_t)l * 3 * D_ * D_;
        const float* co = outw  + (size_t)l * D_ * D_;
        const float* cu = upw   + (size_t)l * FF_ * D_;
        const float* cd = downw + (size_t)l * D_ * FF_;

        if (l == 0)
            embed_ln_cast<<<3072, 256, 0, stream>>>(ids, tok, pos, ln1w, ln1b, x, h,
                                                    cq, co, cu, cd, layerW);
        else
            ln_red4_cast<<<3072, 256, 0, stream>>>(x, P4, ln1w + l * D_, ln1b + l * D_, h,
                                                   cq, co, cu, cd, layerW);

        // QKV GEMM with fused V-transpose epilogue (BM=64, BK=64: grid 576)
        gemm_bt<EPI_QKV, 64, 1><<<32 * (3 * D_ / 128), 256, 0, stream>>>(
            h, qkvwB, qkv, vt, 3 * D_, D_, D_);

        attn_mfma<<<B_ * H_ * (T_ / 16), 64, 0, stream>>>(qkv, vt, o);

        // out-proj: split-K KS=4 (grid 768, 3 K-steps), bf16 partials -> P4
        gemm_bt<EPI_PART, 64, 4><<<32 * (D_ / 128) * 4, 256, 0, stream>>>(
            o, outwB, P4, nullptr, D_, D_, D_ / 4);

        ln_red4<<<BT_, 256, 0, stream>>>(x, P4, ln2w + l * D_, ln2b + l * D_, h);

        gemm_bt<EPI_GELU, 64, 1><<<32 * (FF_ / 128), 256, 0, stream>>>(
            h, upwB, ffh, nullptr, FF_, D_, D_);

        // down-proj: split-K KS=4 (grid 768, 12 K-steps), bf16 partials -> P4
        gemm_bt<EPI_PART, 64, 4><<<32 * (D_ / 128) * 4, 256, 0, stream>>>(
            ffh, downwB, P4, nullptr, D_, FF_, FF_ / 4);
    }

    ln_red4<<<BT_, 256, 0, stream>>>(x, P4, lnfw, lnfb, h);

    cast_bf16<<<2048, 256, 0, stream>>>(tok, tokW, V_ * D_ / 8);
    gemm256<<<(2048 / 256) * (V_ / 256), 512, 0, stream>>>(h, tokW, out, V_, D_);
}